// Round 6
// baseline (983.905 us; speedup 1.0000x reference)
//
#include <hip/hip_runtime.h>
#include <cstdint>

#define N_NODES 100000
#define N_EDGES 1600000
#define F 128
#define OUT_CLS 40
#define LW 13          // waves per k_linear block
#define LBM (LW * 32)  // 416 rows per block -> grid 241 <= 256 CUs (single round)
#define BSHIFT 10      // coarse bucket = dst >> 10 (1024 nodes)
#define NBUCK 98       // ceil(100000/1024)
#define TILE 2048      // edges per k_bscatter block

using f32x16 = __attribute__((ext_vector_type(16))) float;
using bf16x8 = __attribute__((ext_vector_type(8))) short;
using f16x2 = __attribute__((ext_vector_type(2))) _Float16;

// ---- edge accessor: flag=1 means int64 storage (little-endian low word at 2*idx) ----
__device__ __forceinline__ int edge_val(const int* eb, int is64, long idx) {
  return is64 ? eb[2 * idx] : eb[idx];
}

__global__ void k_detect(const unsigned int* eb, int* flag) {
  if (threadIdx.x == 0 && blockIdx.x == 0) {
    int is64 = 1;
#pragma unroll
    for (int i = 1; i < 16; i += 2) is64 &= (eb[i] == 0u);
    flag[0] = is64;
  }
}

// coarse histogram: 98 buckets via LDS, one global atomic per bucket per block
#define CH_E 16
__global__ __launch_bounds__(256) void k_chist(const int* __restrict__ eb, const int* __restrict__ flag,
                                               int* __restrict__ bhist) {
  __shared__ int lh[NBUCK];
  int t = threadIdx.x;
  if (t < NBUCK) lh[t] = 0;
  __syncthreads();
  int is64 = flag[0];
  long base = (long)blockIdx.x * (256 * CH_E);
#pragma unroll
  for (int i = 0; i < CH_E; ++i) {
    long e = base + (long)i * 256 + t;
    if (e < N_EDGES) {
      int d = edge_val(eb, is64, (long)N_EDGES + e);
      atomicAdd(&lh[d >> BSHIFT], 1);
    }
  }
  __syncthreads();
  if (t < NBUCK && lh[t]) atomicAdd(&bhist[t], lh[t]);
}

// scan 98 bucket sums -> boff[0..98]; init bkt_cursor; off[N_NODES]=N_EDGES
__global__ __launch_bounds__(128) void k_bscan(const int* __restrict__ bhist, int* __restrict__ boff,
                                               int* __restrict__ bkt_cursor, int* __restrict__ off) {
  __shared__ int sh[128];
  int t = threadIdx.x;
  int v = (t < NBUCK) ? bhist[t] : 0;
  sh[t] = v;
  __syncthreads();
  for (int d = 1; d < 128; d <<= 1) {
    int u = (t >= d) ? sh[t - d] : 0;
    __syncthreads();
    sh[t] += u;
    __syncthreads();
  }
  int incl = sh[t];
  if (t < NBUCK) {
    boff[t] = incl - v;
    bkt_cursor[t] = incl - v;
  }
  if (t == NBUCK - 1) boff[NBUCK] = incl;
  if (t == 0) off[N_NODES] = N_EDGES;
}

// coarse scatter: LDS counting-sort a 2048-edge tile by bucket, reserve per-bucket global
// runs (one atomic/bucket/tile), copy out coalesced -> each 64B line of ebuf written by ~1 block.
__global__ __launch_bounds__(256) void k_bscatter(const int* __restrict__ eb, const int* __restrict__ flag,
                                                  int* __restrict__ bkt_cursor, uint2* __restrict__ ebuf) {
  __shared__ int lhist[128];
  __shared__ int lbase[128];
  __shared__ int gbase[NBUCK];
  __shared__ int lcnt[NBUCK];
  __shared__ uint2 buf[TILE];
  __shared__ int slotpos[TILE];
  int t = threadIdx.x;
  long e0 = (long)blockIdx.x * TILE;
  int is64 = flag[0];
  if (t < 128) lhist[t] = 0;
  __syncthreads();
#pragma unroll
  for (int i = 0; i < TILE / 256; ++i) {
    long e = e0 + t + i * 256;
    if (e < N_EDGES) {
      int d = edge_val(eb, is64, (long)N_EDGES + e);
      atomicAdd(&lhist[d >> BSHIFT], 1);
    }
  }
  __syncthreads();
  if (t < 128) lbase[t] = lhist[t];
  __syncthreads();
  for (int d = 1; d < 128; d <<= 1) {
    int v = (t >= d && t < 128) ? lbase[t - d] : 0;
    __syncthreads();
    if (t < 128) lbase[t] += v;
    __syncthreads();
  }
  if (t < NBUCK) {
    gbase[t] = atomicAdd(&bkt_cursor[t], lhist[t]);
    lcnt[t] = 0;
  }
  __syncthreads();
#pragma unroll
  for (int i = 0; i < TILE / 256; ++i) {
    long e = e0 + t + i * 256;
    if (e < N_EDGES) {
      int d = edge_val(eb, is64, (long)N_EDGES + e);
      int s = edge_val(eb, is64, e);
      int b = d >> BSHIFT;
      int n = atomicAdd(&lcnt[b], 1);
      int slot = lbase[b] - lhist[b] + n;
      buf[slot] = make_uint2((unsigned)s, (unsigned)d);
      slotpos[slot] = gbase[b] + n;
    }
  }
  __syncthreads();
  int tile_n = (int)min((long)TILE, (long)N_EDGES - e0);
  for (int i = t; i < tile_n; i += 256) {
    ebuf[slotpos[i]] = buf[i];
  }
}

// per-bucket fine sort: LDS 1024-bin histogram + wave-shuffle scan -> off[node], then
// LDS-cursor scatter of srcs.
__global__ __launch_bounds__(1024) void k_fsort(const uint2* __restrict__ ebuf, const int* __restrict__ boff,
                                                int* __restrict__ off, int* __restrict__ srcs) {
  __shared__ int hist[1024];
  __shared__ int cur[1024];
  __shared__ int wsum[16];
  int b = blockIdx.x;
  int t = threadIdx.x;
  int p0 = boff[b], p1 = boff[b + 1];
  hist[t] = 0;
  __syncthreads();
  for (int p = p0 + t; p < p1; p += 1024) {
    int d = (int)ebuf[p].y & 1023;
    atomicAdd(&hist[d], 1);
  }
  __syncthreads();
  // exclusive scan of hist[0..1024): per-wave shfl scan + wave-total scan
  int h = hist[t];
  int v = h;
#pragma unroll
  for (int o = 1; o < 64; o <<= 1) {
    int u = __shfl_up(v, o);
    if ((t & 63) >= o) v += u;
  }
  if ((t & 63) == 63) wsum[t >> 6] = v;
  __syncthreads();
  if (t < 64) {
    int w = (t < 16) ? wsum[t] : 0;
#pragma unroll
    for (int o = 1; o < 16; o <<= 1) {
      int u = __shfl_up(w, o);
      if (t >= o) w += u;
    }
    if (t < 16) wsum[t] = w;
  }
  __syncthreads();
  int base = (t >> 6) ? wsum[(t >> 6) - 1] : 0;
  int gpos = p0 + base + v - h;  // exclusive prefix
  int node = (b << BSHIFT) + t;
  if (node < N_NODES) off[node] = gpos;
  cur[t] = gpos;
  __syncthreads();
  for (int p = p0 + t; p < p1; p += 1024) {
    uint2 sd = ebuf[p];
    int pos = atomicAdd(&cur[(int)sd.y & 1023], 1);
    srcs[pos] = (int)sd.x;
  }
}

// fp32 -> fp16 slice-major copy: o[sl][n][16] with sl = feature/16. Thread c handles 8 fp16:
// (sl, n, h) = c -> writes 16B contiguous; reads 32B from row n.
__global__ __launch_bounds__(256) void k_tohalf(const float* __restrict__ in, _Float16* __restrict__ o) {
  int c = blockIdx.x * 256 + threadIdx.x;
  if (c >= N_NODES * F / 8) return;
  int h = c & 1;
  int n = (c >> 1) % N_NODES;
  int sl = (c >> 1) / N_NODES;
  const float* src = in + (size_t)n * F + sl * 16 + h * 8;
  float4 a = *reinterpret_cast<const float4*>(src);
  float4 b = *reinterpret_cast<const float4*>(src + 4);
  union {
    _Float16 hh[8];
    uint4 u;
  } r;
  r.hh[0] = (_Float16)a.x; r.hh[1] = (_Float16)a.y; r.hh[2] = (_Float16)a.z; r.hh[3] = (_Float16)a.w;
  r.hh[4] = (_Float16)b.x; r.hh[5] = (_Float16)b.y; r.hh[6] = (_Float16)b.z; r.hh[7] = (_Float16)b.w;
  *reinterpret_cast<uint4*>(o + (size_t)c * 8) = r.u;
}

// XCD-feature-sliced gather: slice = blockIdx%8 -> XCD id (round-robin dispatch), each XCD
// reads only its 3.2MB slice plane xs[sl] = [N][16] fp16 -> L2-resident. Lane = (edge-subgroup g,
// feature-pair fo): one f16x2 load covers 8 edges/instruction. srcs broadcast via __shfl.
__global__ __launch_bounds__(256) void k_aggregate(const _Float16* __restrict__ xs,  // [8][N][16]
                                                   const int* __restrict__ off,
                                                   const int* __restrict__ srcs, float* __restrict__ agg) {
  int sl = blockIdx.x & 7;
  int chunk = blockIdx.x >> 3;
  int w = threadIdx.x >> 6;
  int l = threadIdx.x & 63;
  int g = l >> 3;        // edge subgroup 0..7
  int fo = (l & 7) * 2;  // feature offset within slice (fp16 units)
  const _Float16* xb = xs + (size_t)sl * N_NODES * 16;
  int n0 = chunk * 32 + w * 8;
  for (int ni = 0; ni < 8; ++ni) {
    int n = n0 + ni;
    if (n >= N_NODES) return;
    int p0 = __builtin_nontemporal_load(off + n);
    int p1 = __builtin_nontemporal_load(off + n + 1);
    int deg = p1 - p0;
    float s0 = 0.f, s1 = 0.f;
    for (int base = 0; base < deg; base += 64) {
      int rem = deg - base;
      int cnt = (rem < 64) ? rem : 64;
      int my = (l < cnt) ? __builtin_nontemporal_load(srcs + p0 + base + l) : 0;
      for (int j = 0; j < cnt; j += 8) {
        int idx = j + g;
        int s = __shfl(my, idx);
        f16x2 v = *reinterpret_cast<const f16x2*>(xb + (size_t)(unsigned)s * 16 + fo);
        if (idx < cnt) {
          s0 += (float)v[0];
          s1 += (float)v[1];
        }
      }
    }
    s0 += __shfl_xor(s0, 8);
    s1 += __shfl_xor(s1, 8);
    s0 += __shfl_xor(s0, 16);
    s1 += __shfl_xor(s1, 16);
    s0 += __shfl_xor(s0, 32);
    s1 += __shfl_xor(s1, 32);
    float inv = 1.0f / (float)((deg > 1) ? deg : 1);
    if (l < 8) {
      float2 r;
      r.x = s0 * inv;
      r.y = s1 * inv;
      *reinterpret_cast<float2*>(agg + (size_t)n * F + sl * 16 + l * 2) = r;
    }
  }
}

// ---- split fp32 -> bf16 hi/lo (truncation; lo compensates, net rel err ~3*2^-16) ----
__device__ __forceinline__ void split_pack(const float4& a, const float4& b, bf16x8& hi, bf16x8& lo) {
  float f[8] = {a.x, a.y, a.z, a.w, b.x, b.y, b.z, b.w};
#pragma unroll
  for (int i = 0; i < 8; ++i) {
    union { float f; unsigned u; } u0;
    u0.f = f[i];
    hi[i] = (short)(u0.u >> 16);
    union { unsigned u; float f; } uh;
    uh.u = u0.u & 0xFFFF0000u;
    union { float f; unsigned u; } ur;
    ur.f = f[i] - uh.f;
    lo[i] = (short)(ur.u >> 16);
  }
}

// pre-split weights: Wl/Wr per layer -> wsp[layer][4][128*128] bf16 (WlH, WlL, WrH, WrL)
__global__ __launch_bounds__(256) void k_wsplit(const float* __restrict__ Wl1, const float* __restrict__ Wr1,
                                                const float* __restrict__ Wl2, const float* __restrict__ Wr2,
                                                const float* __restrict__ Wl3, const float* __restrict__ Wr3,
                                                unsigned short* __restrict__ wsp) {
  int e = blockIdx.x * 256 + threadIdx.x;  // 0..49151
  if (e >= 3 * 16384) return;
  int L = e >> 14, off = e & 16383;
  const float* wl = (L == 0) ? Wl1 : (L == 1) ? Wl2 : Wl3;
  const float* wr = (L == 0) ? Wr1 : (L == 1) ? Wr2 : Wr3;
  unsigned short* base = wsp + (size_t)L * 4 * 16384;
  {
    union { float f; unsigned u; } u0;
    u0.f = wl[off];
    union { unsigned u; float f; } uh;
    uh.u = u0.u & 0xFFFF0000u;
    union { float f; unsigned u; } ur;
    ur.f = u0.f - uh.f;
    base[off] = (unsigned short)(u0.u >> 16);
    base[16384 + off] = (unsigned short)(ur.u >> 16);
  }
  {
    union { float f; unsigned u; } u0;
    u0.f = wr[off];
    union { unsigned u; float f; } uh;
    uh.u = u0.u & 0xFFFF0000u;
    union { float f; unsigned u; } ur;
    ur.f = u0.f - uh.f;
    base[2 * 16384 + off] = (unsigned short)(u0.u >> 16);
    base[3 * 16384 + off] = (unsigned short)(ur.u >> 16);
  }
}

// out[n][j] = normalize(dot(agg[n],Wl[j]) + dot(x[n],Wr[j]) + bl[j]) [+relu], split-bf16 MFMA.
// 13 waves x 1 row-tile of 32 -> grid 241 (single dispatch round, no 2-block CU tail).
// Depth-1 software pipeline on the per-ks agg/x row loads hides HBM/L2 latency.
// out16 (fp16 copy for next layer's gather) is written SLICE-MAJOR: [8][N][16].
__global__ __launch_bounds__(832, 1) void k_linear(const float* __restrict__ agg, const float* __restrict__ x,
                                                   const unsigned short* __restrict__ wsp,  // [4][128][128]
                                                   const float* __restrict__ bl, float* out,
                                                   _Float16* __restrict__ out16, int relu) {
  __shared__ unsigned short wlds[4][128][136];  // +8 pad: b128 frag reads ~2-way max
  int tid = threadIdx.x;

  for (int c = tid; c < 4 * 2048; c += 832) {
    int m = c >> 11, rem = c & 2047;
    int j = rem >> 4, kc = (rem & 15) * 8;
    uint4 v = *reinterpret_cast<const uint4*>(wsp + (size_t)m * 16384 + j * 128 + kc);
    *reinterpret_cast<uint4*>(&wlds[m][j][kc]) = v;
  }
  __syncthreads();

  int wid = tid >> 6, lane = tid & 63;
  int l31 = lane & 31, lhi = lane >> 5;
  long rb = (long)blockIdx.x * LBM + (long)wid * 32;
  if (rb >= N_NODES) return;  // whole-wave out of range (after barrier)

  int r0 = (int)min(rb + l31, (long)N_NODES - 1);
  const float* a0p = agg + (size_t)r0 * F + lhi * 8;
  const float* x0p = x + (size_t)r0 * F + lhi * 8;

  f32x16 acc[4];
#pragma unroll
  for (int ct = 0; ct < 4; ++ct) acc[ct] = (f32x16)0.f;

  float4 ap = *reinterpret_cast<const float4*>(a0p);
  float4 aq = *reinterpret_cast<const float4*>(a0p + 4);
  float4 xp = *reinterpret_cast<const float4*>(x0p);
  float4 xq = *reinterpret_cast<const float4*>(x0p + 4);

#pragma unroll
  for (int ks = 0; ks < 8; ++ks) {
    float4 ap_n, aq_n, xp_n, xq_n;
    if (ks < 7) {
      const float* an = a0p + (ks + 1) * 16;
      const float* xn = x0p + (ks + 1) * 16;
      ap_n = *reinterpret_cast<const float4*>(an);
      aq_n = *reinterpret_cast<const float4*>(an + 4);
      xp_n = *reinterpret_cast<const float4*>(xn);
      xq_n = *reinterpret_cast<const float4*>(xn + 4);
    }
    int k0 = ks * 16 + lhi * 8;
    bf16x8 aH0, aL0, xH0, xL0;
    split_pack(ap, aq, aH0, aL0);
    split_pack(xp, xq, xH0, xL0);
#pragma unroll
    for (int ct = 0; ct < 4; ++ct) {
      int j = ct * 32 + l31;
      bf16x8 BlH = *reinterpret_cast<const bf16x8*>(&wlds[0][j][k0]);
      bf16x8 BlL = *reinterpret_cast<const bf16x8*>(&wlds[1][j][k0]);
      bf16x8 BrH = *reinterpret_cast<const bf16x8*>(&wlds[2][j][k0]);
      bf16x8 BrL = *reinterpret_cast<const bf16x8*>(&wlds[3][j][k0]);
      acc[ct] = __builtin_amdgcn_mfma_f32_32x32x16_bf16(aH0, BlH, acc[ct], 0, 0, 0);
      acc[ct] = __builtin_amdgcn_mfma_f32_32x32x16_bf16(aL0, BlH, acc[ct], 0, 0, 0);
      acc[ct] = __builtin_amdgcn_mfma_f32_32x32x16_bf16(aH0, BlL, acc[ct], 0, 0, 0);
      acc[ct] = __builtin_amdgcn_mfma_f32_32x32x16_bf16(xH0, BrH, acc[ct], 0, 0, 0);
      acc[ct] = __builtin_amdgcn_mfma_f32_32x32x16_bf16(xL0, BrH, acc[ct], 0, 0, 0);
      acc[ct] = __builtin_amdgcn_mfma_f32_32x32x16_bf16(xH0, BrL, acc[ct], 0, 0, 0);
    }
    ap = ap_n;
    aq = aq_n;
    xp = xp_n;
    xq = xq_n;
  }

  // epilogue: +bias, row L2-norm across 32 lanes (same lhi), optional relu, masked store (+fp16 copy).
#pragma unroll
  for (int ct = 0; ct < 4; ++ct) {
    float b = bl[ct * 32 + l31];
#pragma unroll
    for (int i = 0; i < 16; ++i) acc[ct][i] += b;
  }
#pragma unroll
  for (int i = 0; i < 16; ++i) {
    float ss = acc[0][i] * acc[0][i] + acc[1][i] * acc[1][i] +
               acc[2][i] * acc[2][i] + acc[3][i] * acc[3][i];
#pragma unroll
    for (int o = 1; o < 32; o <<= 1) ss += __shfl_xor(ss, o);
    float inv = 1.0f / fmaxf(sqrtf(ss), 1e-12f);
    long grow = rb + (i & 3) + 8 * (i >> 2) + 4 * lhi;
    if (grow < N_NODES) {
      long base = grow * F + l31;
#pragma unroll
      for (int ct = 0; ct < 4; ++ct) {
        float v = acc[ct][i] * inv;
        if (relu) v = fmaxf(v, 0.f);
        out[base + ct * 32] = v;
        if (out16) {
          int f = ct * 32 + l31;
          out16[((size_t)(f >> 4) * N_NODES + grow) * 16 + (f & 15)] = (_Float16)v;
        }
      }
    }
  }
}

// 32 nodes/block (grid = N_NODES/32 = 3125); Wfc + h tile in LDS; 8 threads/node x 5 classes
#define FCP 132
__global__ __launch_bounds__(256) void k_fc_softmax(const float* __restrict__ h, const float* __restrict__ Wfc,
                                                    const float* __restrict__ bfc, float* __restrict__ out) {
  __shared__ float w_s[OUT_CLS][FCP];
  __shared__ float h_s[32][FCP];
  int tid = threadIdx.x;
  int nb = blockIdx.x * 32;

  for (int i = tid; i < OUT_CLS * (F / 4); i += 256) {
    int r = i >> 5, c = (i & 31) * 4;
    *reinterpret_cast<float4*>(&w_s[r][c]) = *reinterpret_cast<const float4*>(Wfc + (size_t)r * F + c);
  }
  for (int i = tid; i < 32 * (F / 4); i += 256) {
    int r = i >> 5, c = (i & 31) * 4;
    *reinterpret_cast<float4*>(&h_s[r][c]) = *reinterpret_cast<const float4*>(h + (size_t)(nb + r) * F + c);
  }
  __syncthreads();

  int r = tid >> 3, sub = tid & 7;
  float acc[5];
#pragma unroll
  for (int c = 0; c < 5; ++c) acc[c] = bfc[sub * 5 + c];

  for (int k4 = 0; k4 < F / 4; ++k4) {
    float4 hv = *reinterpret_cast<const float4*>(&h_s[r][k4 * 4]);
#pragma unroll
    for (int c = 0; c < 5; ++c) {
      float4 wv = *reinterpret_cast<const float4*>(&w_s[sub * 5 + c][k4 * 4]);
      acc[c] += hv.x * wv.x + hv.y * wv.y + hv.z * wv.z + hv.w * wv.w;
    }
  }

  float m = acc[0];
#pragma unroll
  for (int c = 1; c < 5; ++c) m = fmaxf(m, acc[c]);
#pragma unroll
  for (int o = 4; o > 0; o >>= 1) m = fmaxf(m, __shfl_xor(m, o));
  float e[5], s = 0.f;
#pragma unroll
  for (int c = 0; c < 5; ++c) {
    e[c] = expf(acc[c] - m);
    s += e[c];
  }
#pragma unroll
  for (int o = 4; o > 0; o >>= 1) s += __shfl_xor(s, o);
  float inv = 1.0f / s;
#pragma unroll
  for (int c = 0; c < 5; ++c) out[(size_t)(nb + r) * OUT_CLS + sub * 5 + c] = e[c] * inv;
}

extern "C" void kernel_launch(void* const* d_in, const int* in_sizes, int n_in, void* d_out, int out_size,
                              void* d_ws, size_t ws_size, hipStream_t stream) {
  const float* feat = (const float*)d_in[0];
  const int* eb = (const int*)d_in[1];
  const float* Wl1 = (const float*)d_in[2];
  const float* bl1 = (const float*)d_in[3];
  const float* Wr1 = (const float*)d_in[4];
  const float* Wl2 = (const float*)d_in[5];
  const float* bl2 = (const float*)d_in[6];
  const float* Wr2 = (const float*)d_in[7];
  const float* Wl3 = (const float*)d_in[8];
  const float* bl3 = (const float*)d_in[9];
  const float* Wr3 = (const float*)d_in[10];
  const float* Wfc = (const float*)d_in[11];
  const float* bfc = (const float*)d_in[12];
  float* out = (float*)d_out;

  char* w = (char*)d_ws;
  auto alloc = [&](size_t bytes) {
    char* p = w;
    w += (bytes + 255) & ~(size_t)255;
    return p;
  };
  int* flag = (int*)alloc(4);
  int* bhist = (int*)alloc((size_t)NBUCK * 4);
  int* boff = (int*)alloc((size_t)(NBUCK + 1) * 4);
  int* off = (int*)alloc((size_t)(N_NODES + 1) * 4);
  int* srcs = (int*)alloc((size_t)N_EDGES * 4 + 256);  // +pad: gather src block may overread 64 ints
  int* bkt_cursor = (int*)alloc((size_t)NBUCK * 4);
  unsigned short* wsp = (unsigned short*)alloc((size_t)3 * 4 * 16384 * 2);
  float* bufA = (float*)alloc((size_t)N_NODES * F * 4);
  float* bufB = (float*)alloc((size_t)N_NODES * F * 4);
  _Float16* h16X = (_Float16*)alloc((size_t)N_NODES * F * 2);  // feat16, later h2_16 (slice-major)
  _Float16* h16A = (_Float16*)alloc((size_t)N_NODES * F * 2);  // h1_16 (slice-major)
  uint2* ebuf = (uint2*)bufB;  // dead before bufB's first use (layer-2 aggregate)
  (void)ws_size;
  (void)in_sizes;
  (void)n_in;
  (void)out_size;

  hipMemsetAsync(bhist, 0, (size_t)NBUCK * 4, stream);
  k_detect<<<1, 64, 0, stream>>>((const unsigned int*)eb, flag);
  k_chist<<<(N_EDGES + 256 * CH_E - 1) / (256 * CH_E), 256, 0, stream>>>(eb, flag, bhist);
  k_bscan<<<1, 128, 0, stream>>>(bhist, boff, bkt_cursor, off);
  k_bscatter<<<(N_EDGES + TILE - 1) / TILE, 256, 0, stream>>>(eb, flag, bkt_cursor, ebuf);
  k_fsort<<<NBUCK, 1024, 0, stream>>>(ebuf, boff, off, srcs);
  k_wsplit<<<192, 256, 0, stream>>>(Wl1, Wr1, Wl2, Wr2, Wl3, Wr3, wsp);
  k_tohalf<<<(N_NODES * F / 8 + 255) / 256, 256, 0, stream>>>(feat, h16X);

  const int nag = 8 * ((N_NODES + 31) / 32);   // 25000: slice = bid%8 (XCD), chunk = bid/8
  const int nlin = (N_NODES + LBM - 1) / LBM;  // 241 (single round on 256 CUs)
  const int nfc = N_NODES / 32;                // 3125

  // layer 1: in=feat (h16X=feat16) -> bufA (+h16A)
  k_aggregate<<<nag, 256, 0, stream>>>(h16X, off, srcs, bufA);
  k_linear<<<nlin, 832, 0, stream>>>(bufA, feat, wsp + 0 * 4 * 16384, bl1, bufA, h16A, 1);
  // layer 2: in=bufA (h16A) -> bufB (+h16X reused as h2_16)
  k_aggregate<<<nag, 256, 0, stream>>>(h16A, off, srcs, bufB);
  k_linear<<<nlin, 832, 0, stream>>>(bufB, bufA, wsp + 1 * 4 * 16384, bl2, bufB, h16X, 1);
  // layer 3: in=bufB (h16X) -> bufA
  k_aggregate<<<nag, 256, 0, stream>>>(h16X, off, srcs, bufA);
  k_linear<<<nlin, 832, 0, stream>>>(bufA, bufB, wsp + 2 * 4 * 16384, bl3, bufA, ((_Float16*)0), 0);
  // FC + softmax
  k_fc_softmax<<<nfc, 256, 0, stream>>>(bufA, Wfc, bfc, out);
}

// Round 7
// 407.413 us; speedup vs baseline: 2.4150x; 2.4150x over previous
//
#include <hip/hip_runtime.h>
#include <cstdint>

#define N_NODES 100000
#define N_EDGES 1600000
#define F 128
#define OUT_CLS 40
#define LW 13          // waves per k_linear block
#define LBM (LW * 32)  // 416 rows per block -> grid 241 <= 256 CUs (single round)
#define BSHIFT 10      // coarse bucket = dst >> 10 (1024 nodes)
#define NBUCK 98       // ceil(100000/1024)
#define TILE 2048      // edges per k_bscatter block

using f32x16 = __attribute__((ext_vector_type(16))) float;
using bf16x8 = __attribute__((ext_vector_type(8))) short;
using f16x2 = __attribute__((ext_vector_type(2))) _Float16;

// ---- edge accessor: flag=1 means int64 storage (little-endian low word at 2*idx) ----
__device__ __forceinline__ int edge_val(const int* eb, int is64, long idx) {
  return is64 ? eb[2 * idx] : eb[idx];
}

__global__ void k_detect(const unsigned int* eb, int* flag) {
  if (threadIdx.x == 0 && blockIdx.x == 0) {
    int is64 = 1;
#pragma unroll
    for (int i = 1; i < 16; i += 2) is64 &= (eb[i] == 0u);
    flag[0] = is64;
  }
}

// coarse histogram: 98 buckets via LDS, one global atomic per bucket per block
#define CH_E 16
__global__ __launch_bounds__(256) void k_chist(const int* __restrict__ eb, const int* __restrict__ flag,
                                               int* __restrict__ bhist) {
  __shared__ int lh[NBUCK];
  int t = threadIdx.x;
  if (t < NBUCK) lh[t] = 0;
  __syncthreads();
  int is64 = flag[0];
  long base = (long)blockIdx.x * (256 * CH_E);
#pragma unroll
  for (int i = 0; i < CH_E; ++i) {
    long e = base + (long)i * 256 + t;
    if (e < N_EDGES) {
      int d = edge_val(eb, is64, (long)N_EDGES + e);
      atomicAdd(&lh[d >> BSHIFT], 1);
    }
  }
  __syncthreads();
  if (t < NBUCK && lh[t]) atomicAdd(&bhist[t], lh[t]);
}

// scan 98 bucket sums -> boff[0..98]; init bkt_cursor; off[N_NODES]=N_EDGES
__global__ __launch_bounds__(128) void k_bscan(const int* __restrict__ bhist, int* __restrict__ boff,
                                               int* __restrict__ bkt_cursor, int* __restrict__ off) {
  __shared__ int sh[128];
  int t = threadIdx.x;
  int v = (t < NBUCK) ? bhist[t] : 0;
  sh[t] = v;
  __syncthreads();
  for (int d = 1; d < 128; d <<= 1) {
    int u = (t >= d) ? sh[t - d] : 0;
    __syncthreads();
    sh[t] += u;
    __syncthreads();
  }
  int incl = sh[t];
  if (t < NBUCK) {
    boff[t] = incl - v;
    bkt_cursor[t] = incl - v;
  }
  if (t == NBUCK - 1) boff[NBUCK] = incl;
  if (t == 0) off[N_NODES] = N_EDGES;
}

// coarse scatter: LDS counting-sort a 2048-edge tile by bucket, reserve per-bucket global
// runs (one atomic/bucket/tile), copy out coalesced. ebuf entry packed: src | (dst&1023)<<17
// (src < 2^17, 27 bits total) -> half the scatter write / fsort read traffic of uint2.
__global__ __launch_bounds__(256) void k_bscatter(const int* __restrict__ eb, const int* __restrict__ flag,
                                                  int* __restrict__ bkt_cursor, unsigned* __restrict__ ebuf) {
  __shared__ int lhist[128];
  __shared__ int lbase[128];
  __shared__ int gbase[NBUCK];
  __shared__ int lcnt[NBUCK];
  __shared__ unsigned buf[TILE];
  __shared__ int slotpos[TILE];
  int t = threadIdx.x;
  long e0 = (long)blockIdx.x * TILE;
  int is64 = flag[0];
  if (t < 128) lhist[t] = 0;
  __syncthreads();
#pragma unroll
  for (int i = 0; i < TILE / 256; ++i) {
    long e = e0 + t + i * 256;
    if (e < N_EDGES) {
      int d = edge_val(eb, is64, (long)N_EDGES + e);
      atomicAdd(&lhist[d >> BSHIFT], 1);
    }
  }
  __syncthreads();
  if (t < 128) lbase[t] = lhist[t];
  __syncthreads();
  for (int d = 1; d < 128; d <<= 1) {
    int v = (t >= d && t < 128) ? lbase[t - d] : 0;
    __syncthreads();
    if (t < 128) lbase[t] += v;
    __syncthreads();
  }
  if (t < NBUCK) {
    gbase[t] = atomicAdd(&bkt_cursor[t], lhist[t]);
    lcnt[t] = 0;
  }
  __syncthreads();
#pragma unroll
  for (int i = 0; i < TILE / 256; ++i) {
    long e = e0 + t + i * 256;
    if (e < N_EDGES) {
      int d = edge_val(eb, is64, (long)N_EDGES + e);
      int s = edge_val(eb, is64, e);
      int b = d >> BSHIFT;
      int n = atomicAdd(&lcnt[b], 1);
      int slot = lbase[b] - lhist[b] + n;
      buf[slot] = (unsigned)s | ((unsigned)(d & 1023) << 17);
      slotpos[slot] = gbase[b] + n;
    }
  }
  __syncthreads();
  int tile_n = (int)min((long)TILE, (long)N_EDGES - e0);
  for (int i = t; i < tile_n; i += 256) {
    ebuf[slotpos[i]] = buf[i];
  }
}

// per-bucket fine sort: LDS 1024-bin histogram + wave-shuffle scan -> off[node], then
// LDS-cursor scatter of srcs. Packed ebuf: d10 = e>>17, src = e & 0x1FFFF.
__global__ __launch_bounds__(1024) void k_fsort(const unsigned* __restrict__ ebuf, const int* __restrict__ boff,
                                                int* __restrict__ off, int* __restrict__ srcs) {
  __shared__ int hist[1024];
  __shared__ int cur[1024];
  __shared__ int wsum[16];
  int b = blockIdx.x;
  int t = threadIdx.x;
  int p0 = boff[b], p1 = boff[b + 1];
  hist[t] = 0;
  __syncthreads();
  for (int p = p0 + t; p < p1; p += 1024) {
    int d = (int)(ebuf[p] >> 17);
    atomicAdd(&hist[d], 1);
  }
  __syncthreads();
  // exclusive scan of hist[0..1024): per-wave shfl scan + wave-total scan
  int h = hist[t];
  int v = h;
#pragma unroll
  for (int o = 1; o < 64; o <<= 1) {
    int u = __shfl_up(v, o);
    if ((t & 63) >= o) v += u;
  }
  if ((t & 63) == 63) wsum[t >> 6] = v;
  __syncthreads();
  if (t < 64) {
    int w = (t < 16) ? wsum[t] : 0;
#pragma unroll
    for (int o = 1; o < 16; o <<= 1) {
      int u = __shfl_up(w, o);
      if (t >= o) w += u;
    }
    if (t < 16) wsum[t] = w;
  }
  __syncthreads();
  int base = (t >> 6) ? wsum[(t >> 6) - 1] : 0;
  int gpos = p0 + base + v - h;  // exclusive prefix
  int node = (b << BSHIFT) + t;
  if (node < N_NODES) off[node] = gpos;
  cur[t] = gpos;
  __syncthreads();
  for (int p = p0 + t; p < p1; p += 1024) {
    unsigned e = ebuf[p];
    int pos = atomicAdd(&cur[(int)(e >> 17)], 1);
    srcs[pos] = (int)(e & 0x1FFFFu);
  }
}

// fp32 -> fp16 copy (RN), 8 elems/thread, row-major
__global__ __launch_bounds__(256) void k_tohalf(const float* __restrict__ in, _Float16* __restrict__ o) {
  int i = blockIdx.x * 256 + threadIdx.x;
  if (i >= N_NODES * F / 8) return;
  float4 a = reinterpret_cast<const float4*>(in)[2 * i];
  float4 b = reinterpret_cast<const float4*>(in)[2 * i + 1];
  union {
    _Float16 h[8];
    uint4 u;
  } r;
  r.h[0] = (_Float16)a.x; r.h[1] = (_Float16)a.y; r.h[2] = (_Float16)a.z; r.h[3] = (_Float16)a.w;
  r.h[4] = (_Float16)b.x; r.h[5] = (_Float16)b.y; r.h[6] = (_Float16)b.z; r.h[7] = (_Float16)b.w;
  reinterpret_cast<uint4*>(o)[i] = r.u;
}

// one wave per node, fp16 row gather; lane l owns features [2l, 2l+1]; fp32 accumulate.
// src indices batch-loaded 64-at-a-time (one coalesced load) and broadcast via readlane
// -> index fetch off the gather critical path, scalar-base addressing, 8 outstanding rows.
// (Measured 59.5us; the R5 feature-slice variant 8x'd per-node overhead -> reverted.)
__global__ __launch_bounds__(256) void k_aggregate(const _Float16* __restrict__ x, const int* __restrict__ off,
                                                   const int* __restrict__ srcs, float* __restrict__ agg) {
  int n = blockIdx.x * 4 + (threadIdx.x >> 6);
  if (n >= N_NODES) return;
  int l = threadIdx.x & 63;
  int p0 = off[n], p1 = off[n + 1];
  int deg = p1 - p0;
  float sx = 0.f, sy = 0.f;

  for (int base = 0; base < deg; base += 64) {
    int rem = deg - base;
    int cnt = (rem < 64) ? rem : 64;
    int my = (l < cnt) ? srcs[p0 + base + l] : 0;
    int j = 0;
    for (; j + 7 < cnt; j += 8) {
      int s[8];
#pragma unroll
      for (int k = 0; k < 8; ++k) s[k] = __builtin_amdgcn_readlane(my, j + k);
      f16x2 v[8];
#pragma unroll
      for (int k = 0; k < 8; ++k)
        v[k] = *reinterpret_cast<const f16x2*>(x + (size_t)(unsigned)s[k] * F + 2 * l);
#pragma unroll
      for (int k = 0; k < 8; ++k) {
        sx += (float)v[k][0];
        sy += (float)v[k][1];
      }
    }
    for (; j + 3 < cnt; j += 4) {
      int s[4];
#pragma unroll
      for (int k = 0; k < 4; ++k) s[k] = __builtin_amdgcn_readlane(my, j + k);
      f16x2 v[4];
#pragma unroll
      for (int k = 0; k < 4; ++k)
        v[k] = *reinterpret_cast<const f16x2*>(x + (size_t)(unsigned)s[k] * F + 2 * l);
#pragma unroll
      for (int k = 0; k < 4; ++k) {
        sx += (float)v[k][0];
        sy += (float)v[k][1];
      }
    }
    for (; j < cnt; ++j) {
      int s = __builtin_amdgcn_readlane(my, j);
      f16x2 v = *reinterpret_cast<const f16x2*>(x + (size_t)(unsigned)s * F + 2 * l);
      sx += (float)v[0];
      sy += (float)v[1];
    }
  }

  float inv = 1.0f / (float)max(deg, 1);
  float2 r;
  r.x = sx * inv;
  r.y = sy * inv;
  *reinterpret_cast<float2*>(agg + (size_t)n * F + 2 * l) = r;
}

// ---- split fp32 -> bf16 hi/lo (truncation; lo compensates, net rel err ~3*2^-16) ----
__device__ __forceinline__ void split_pack(const float4& a, const float4& b, bf16x8& hi, bf16x8& lo) {
  float f[8] = {a.x, a.y, a.z, a.w, b.x, b.y, b.z, b.w};
#pragma unroll
  for (int i = 0; i < 8; ++i) {
    union { float f; unsigned u; } u0;
    u0.f = f[i];
    hi[i] = (short)(u0.u >> 16);
    union { unsigned u; float f; } uh;
    uh.u = u0.u & 0xFFFF0000u;
    union { float f; unsigned u; } ur;
    ur.f = f[i] - uh.f;
    lo[i] = (short)(ur.u >> 16);
  }
}

// pre-split weights: Wl/Wr per layer -> wsp[layer][4][128*128] bf16 (WlH, WlL, WrH, WrL)
__global__ __launch_bounds__(256) void k_wsplit(const float* __restrict__ Wl1, const float* __restrict__ Wr1,
                                                const float* __restrict__ Wl2, const float* __restrict__ Wr2,
                                                const float* __restrict__ Wl3, const float* __restrict__ Wr3,
                                                unsigned short* __restrict__ wsp) {
  int e = blockIdx.x * 256 + threadIdx.x;  // 0..49151
  if (e >= 3 * 16384) return;
  int L = e >> 14, off = e & 16383;
  const float* wl = (L == 0) ? Wl1 : (L == 1) ? Wl2 : Wl3;
  const float* wr = (L == 0) ? Wr1 : (L == 1) ? Wr2 : Wr3;
  unsigned short* base = wsp + (size_t)L * 4 * 16384;
  {
    union { float f; unsigned u; } u0;
    u0.f = wl[off];
    union { unsigned u; float f; } uh;
    uh.u = u0.u & 0xFFFF0000u;
    union { float f; unsigned u; } ur;
    ur.f = u0.f - uh.f;
    base[off] = (unsigned short)(u0.u >> 16);
    base[16384 + off] = (unsigned short)(ur.u >> 16);
  }
  {
    union { float f; unsigned u; } u0;
    u0.f = wr[off];
    union { unsigned u; float f; } uh;
    uh.u = u0.u & 0xFFFF0000u;
    union { float f; unsigned u; } ur;
    ur.f = u0.f - uh.f;
    base[2 * 16384 + off] = (unsigned short)(u0.u >> 16);
    base[3 * 16384 + off] = (unsigned short)(ur.u >> 16);
  }
}

// out[n][j] = normalize(dot(agg[n],Wl[j]) + dot(x[n],Wr[j]) + bl[j]) [+relu], split-bf16 MFMA.
// 13 waves x 1 row-tile of 32 -> grid 241 (single dispatch round, no 2-block CU tail).
// Depth-1 software pipeline on the per-ks agg/x row loads hides HBM/L2 latency.
__global__ __launch_bounds__(832, 1) void k_linear(const float* __restrict__ agg, const float* __restrict__ x,
                                                   const unsigned short* __restrict__ wsp,  // [4][128][128]
                                                   const float* __restrict__ bl, float* out,
                                                   _Float16* __restrict__ out16, int relu) {
  __shared__ unsigned short wlds[4][128][136];  // +8 pad: b128 frag reads ~2-way max
  int tid = threadIdx.x;

  for (int c = tid; c < 4 * 2048; c += 832) {
    int m = c >> 11, rem = c & 2047;
    int j = rem >> 4, kc = (rem & 15) * 8;
    uint4 v = *reinterpret_cast<const uint4*>(wsp + (size_t)m * 16384 + j * 128 + kc);
    *reinterpret_cast<uint4*>(&wlds[m][j][kc]) = v;
  }
  __syncthreads();

  int wid = tid >> 6, lane = tid & 63;
  int l31 = lane & 31, lhi = lane >> 5;
  long rb = (long)blockIdx.x * LBM + (long)wid * 32;
  if (rb >= N_NODES) return;  // whole-wave out of range (after barrier)

  int r0 = (int)min(rb + l31, (long)N_NODES - 1);
  const float* a0p = agg + (size_t)r0 * F + lhi * 8;
  const float* x0p = x + (size_t)r0 * F + lhi * 8;

  f32x16 acc[4];
#pragma unroll
  for (int ct = 0; ct < 4; ++ct) acc[ct] = (f32x16)0.f;

  float4 ap = *reinterpret_cast<const float4*>(a0p);
  float4 aq = *reinterpret_cast<const float4*>(a0p + 4);
  float4 xp = *reinterpret_cast<const float4*>(x0p);
  float4 xq = *reinterpret_cast<const float4*>(x0p + 4);

#pragma unroll
  for (int ks = 0; ks < 8; ++ks) {
    float4 ap_n, aq_n, xp_n, xq_n;
    if (ks < 7) {
      const float* an = a0p + (ks + 1) * 16;
      const float* xn = x0p + (ks + 1) * 16;
      ap_n = *reinterpret_cast<const float4*>(an);
      aq_n = *reinterpret_cast<const float4*>(an + 4);
      xp_n = *reinterpret_cast<const float4*>(xn);
      xq_n = *reinterpret_cast<const float4*>(xn + 4);
    }
    int k0 = ks * 16 + lhi * 8;
    bf16x8 aH0, aL0, xH0, xL0;
    split_pack(ap, aq, aH0, aL0);
    split_pack(xp, xq, xH0, xL0);
#pragma unroll
    for (int ct = 0; ct < 4; ++ct) {
      int j = ct * 32 + l31;
      bf16x8 BlH = *reinterpret_cast<const bf16x8*>(&wlds[0][j][k0]);
      bf16x8 BlL = *reinterpret_cast<const bf16x8*>(&wlds[1][j][k0]);
      bf16x8 BrH = *reinterpret_cast<const bf16x8*>(&wlds[2][j][k0]);
      bf16x8 BrL = *reinterpret_cast<const bf16x8*>(&wlds[3][j][k0]);
      acc[ct] = __builtin_amdgcn_mfma_f32_32x32x16_bf16(aH0, BlH, acc[ct], 0, 0, 0);
      acc[ct] = __builtin_amdgcn_mfma_f32_32x32x16_bf16(aL0, BlH, acc[ct], 0, 0, 0);
      acc[ct] = __builtin_amdgcn_mfma_f32_32x32x16_bf16(aH0, BlL, acc[ct], 0, 0, 0);
      acc[ct] = __builtin_amdgcn_mfma_f32_32x32x16_bf16(xH0, BrH, acc[ct], 0, 0, 0);
      acc[ct] = __builtin_amdgcn_mfma_f32_32x32x16_bf16(xL0, BrH, acc[ct], 0, 0, 0);
      acc[ct] = __builtin_amdgcn_mfma_f32_32x32x16_bf16(xH0, BrL, acc[ct], 0, 0, 0);
    }
    ap = ap_n;
    aq = aq_n;
    xp = xp_n;
    xq = xq_n;
  }

  // epilogue: +bias, row L2-norm across 32 lanes (same lhi), optional relu, masked store (+fp16 copy).
#pragma unroll
  for (int ct = 0; ct < 4; ++ct) {
    float b = bl[ct * 32 + l31];
#pragma unroll
    for (int i = 0; i < 16; ++i) acc[ct][i] += b;
  }
#pragma unroll
  for (int i = 0; i < 16; ++i) {
    float ss = acc[0][i] * acc[0][i] + acc[1][i] * acc[1][i] +
               acc[2][i] * acc[2][i] + acc[3][i] * acc[3][i];
#pragma unroll
    for (int o = 1; o < 32; o <<= 1) ss += __shfl_xor(ss, o);
    float inv = 1.0f / fmaxf(sqrtf(ss), 1e-12f);
    long grow = rb + (i & 3) + 8 * (i >> 2) + 4 * lhi;
    if (grow < N_NODES) {
      long base = grow * F + l31;
#pragma unroll
      for (int ct = 0; ct < 4; ++ct) {
        float v = acc[ct][i] * inv;
        if (relu) v = fmaxf(v, 0.f);
        out[base + ct * 32] = v;
        if (out16) out16[base + ct * 32] = (_Float16)v;
      }
    }
  }
}

// 32 nodes/block (grid = N_NODES/32 = 3125); Wfc + h tile in LDS; 8 threads/node x 5 classes
#define FCP 132
__global__ __launch_bounds__(256) void k_fc_softmax(const float* __restrict__ h, const float* __restrict__ Wfc,
                                                    const float* __restrict__ bfc, float* __restrict__ out) {
  __shared__ float w_s[OUT_CLS][FCP];
  __shared__ float h_s[32][FCP];
  int tid = threadIdx.x;
  int nb = blockIdx.x * 32;

  for (int i = tid; i < OUT_CLS * (F / 4); i += 256) {
    int r = i >> 5, c = (i & 31) * 4;
    *reinterpret_cast<float4*>(&w_s[r][c]) = *reinterpret_cast<const float4*>(Wfc + (size_t)r * F + c);
  }
  for (int i = tid; i < 32 * (F / 4); i += 256) {
    int r = i >> 5, c = (i & 31) * 4;
    *reinterpret_cast<float4*>(&h_s[r][c]) = *reinterpret_cast<const float4*>(h + (size_t)(nb + r) * F + c);
  }
  __syncthreads();

  int r = tid >> 3, sub = tid & 7;
  float acc[5];
#pragma unroll
  for (int c = 0; c < 5; ++c) acc[c] = bfc[sub * 5 + c];

  for (int k4 = 0; k4 < F / 4; ++k4) {
    float4 hv = *reinterpret_cast<const float4*>(&h_s[r][k4 * 4]);
#pragma unroll
    for (int c = 0; c < 5; ++c) {
      float4 wv = *reinterpret_cast<const float4*>(&w_s[sub * 5 + c][k4 * 4]);
      acc[c] += hv.x * wv.x + hv.y * wv.y + hv.z * wv.z + hv.w * wv.w;
    }
  }

  float m = acc[0];
#pragma unroll
  for (int c = 1; c < 5; ++c) m = fmaxf(m, acc[c]);
#pragma unroll
  for (int o = 4; o > 0; o >>= 1) m = fmaxf(m, __shfl_xor(m, o));
  float e[5], s = 0.f;
#pragma unroll
  for (int c = 0; c < 5; ++c) {
    e[c] = expf(acc[c] - m);
    s += e[c];
  }
#pragma unroll
  for (int o = 4; o > 0; o >>= 1) s += __shfl_xor(s, o);
  float inv = 1.0f / s;
#pragma unroll
  for (int c = 0; c < 5; ++c) out[(size_t)(nb + r) * OUT_CLS + sub * 5 + c] = e[c] * inv;
}

extern "C" void kernel_launch(void* const* d_in, const int* in_sizes, int n_in, void* d_out, int out_size,
                              void* d_ws, size_t ws_size, hipStream_t stream) {
  const float* feat = (const float*)d_in[0];
  const int* eb = (const int*)d_in[1];
  const float* Wl1 = (const float*)d_in[2];
  const float* bl1 = (const float*)d_in[3];
  const float* Wr1 = (const float*)d_in[4];
  const float* Wl2 = (const float*)d_in[5];
  const float* bl2 = (const float*)d_in[6];
  const float* Wr2 = (const float*)d_in[7];
  const float* Wl3 = (const float*)d_in[8];
  const float* bl3 = (const float*)d_in[9];
  const float* Wr3 = (const float*)d_in[10];
  const float* Wfc = (const float*)d_in[11];
  const float* bfc = (const float*)d_in[12];
  float* out = (float*)d_out;

  char* w = (char*)d_ws;
  auto alloc = [&](size_t bytes) {
    char* p = w;
    w += (bytes + 255) & ~(size_t)255;
    return p;
  };
  int* flag = (int*)alloc(4);
  int* bhist = (int*)alloc((size_t)NBUCK * 4);
  int* boff = (int*)alloc((size_t)(NBUCK + 1) * 4);
  int* off = (int*)alloc((size_t)(N_NODES + 1) * 4);
  int* srcs = (int*)alloc((size_t)N_EDGES * 4 + 256);  // +pad: gather src block may overread 64 ints
  int* bkt_cursor = (int*)alloc((size_t)NBUCK * 4);
  unsigned short* wsp = (unsigned short*)alloc((size_t)3 * 4 * 16384 * 2);
  float* bufA = (float*)alloc((size_t)N_NODES * F * 4);
  float* bufB = (float*)alloc((size_t)N_NODES * F * 4);
  _Float16* h16X = (_Float16*)alloc((size_t)N_NODES * F * 2);  // feat16, later h2_16
  _Float16* h16A = (_Float16*)alloc((size_t)N_NODES * F * 2);  // h1_16
  unsigned* ebuf = (unsigned*)bufB;  // dead before bufB's first use (layer-2 aggregate)
  (void)ws_size;
  (void)in_sizes;
  (void)n_in;
  (void)out_size;

  hipMemsetAsync(bhist, 0, (size_t)NBUCK * 4, stream);
  k_detect<<<1, 64, 0, stream>>>((const unsigned int*)eb, flag);
  k_chist<<<(N_EDGES + 256 * CH_E - 1) / (256 * CH_E), 256, 0, stream>>>(eb, flag, bhist);
  k_bscan<<<1, 128, 0, stream>>>(bhist, boff, bkt_cursor, off);
  k_bscatter<<<(N_EDGES + TILE - 1) / TILE, 256, 0, stream>>>(eb, flag, bkt_cursor, ebuf);
  k_fsort<<<NBUCK, 1024, 0, stream>>>(ebuf, boff, off, srcs);
  k_wsplit<<<192, 256, 0, stream>>>(Wl1, Wr1, Wl2, Wr2, Wl3, Wr3, wsp);
  k_tohalf<<<(N_NODES * F / 8 + 255) / 256, 256, 0, stream>>>(feat, h16X);

  const int nag = (N_NODES + 3) / 4;           // one wave per node
  const int nlin = (N_NODES + LBM - 1) / LBM;  // 241 (single round on 256 CUs)
  const int nfc = N_NODES / 32;                // 3125

  // layer 1: in=feat (h16X=feat16) -> bufA (+h16A)
  k_aggregate<<<nag, 256, 0, stream>>>(h16X, off, srcs, bufA);
  k_linear<<<nlin, 832, 0, stream>>>(bufA, feat, wsp + 0 * 4 * 16384, bl1, bufA, h16A, 1);
  // layer 2: in=bufA (h16A) -> bufB (+h16X reused as h2_16)
  k_aggregate<<<nag, 256, 0, stream>>>(h16A, off, srcs, bufB);
  k_linear<<<nlin, 832, 0, stream>>>(bufB, bufA, wsp + 1 * 4 * 16384, bl2, bufB, h16X, 1);
  // layer 3: in=bufB (h16X) -> bufA
  k_aggregate<<<nag, 256, 0, stream>>>(h16X, off, srcs, bufA);
  k_linear<<<nlin, 832, 0, stream>>>(bufA, bufB, wsp + 2 * 4 * 16384, bl3, bufA, ((_Float16*)0), 0);
  // FC + softmax
  k_fc_softmax<<<nfc, 256, 0, stream>>>(bufA, Wfc, bfc, out);
}